// Round 8
// baseline (768.775 us; speedup 1.0000x reference)
//
#include <hip/hip_runtime.h>

#define HEADS 4
#define CH 64
#define HC 256
#define NGRAPH 32
#define NEG_ATT 0.2f
#define NEG_ACT 0.01f

typedef __attribute__((ext_vector_type(8))) short bf16x8;
typedef __attribute__((ext_vector_type(4))) float f32x4;
typedef __attribute__((ext_vector_type(2))) float f32x2;

// split two fp32 into packed hi-bf16 pair and lo-bf16 pair (truncation; lo captures residual)
__device__ __forceinline__ void split2(float a, float b, unsigned& hi, unsigned& lo) {
  unsigned ua = __float_as_uint(a), ub = __float_as_uint(b);
  float la = a - __uint_as_float(ua & 0xFFFF0000u);
  float lb = b - __uint_as_float(ub & 0xFFFF0000u);
  hi = __builtin_amdgcn_perm(ub, ua, 0x07060302u);  // [hi16(b) : hi16(a)]
  lo = __builtin_amdgcn_perm(__float_as_uint(lb), __float_as_uint(la), 0x07060302u);
}

// round-to-nearest-even fp32 -> bf16 (low 16 bits)
__device__ __forceinline__ unsigned rtn_bf16(float f) {
  unsigned u = __float_as_uint(f);
  return (u + 0x7FFFu + ((u >> 16) & 1u)) >> 16;
}

// ---------- conversions ----------
__global__ __launch_bounds__(256) void convert_x(
    const float* __restrict__ X, unsigned short* __restrict__ xhi,
    unsigned short* __restrict__ xlo, int total4) {
  int g = blockIdx.x * 256 + threadIdx.x;
  if (g >= total4) return;
  float4 v = *(const float4*)&X[(size_t)g * 4];
  uint2 h2, l2;
  split2(v.x, v.y, h2.x, l2.x);
  split2(v.z, v.w, h2.y, l2.y);
  *(uint2*)&xhi[(size_t)g * 4] = h2;
  *(uint2*)&xlo[(size_t)g * 4] = l2;
}

// W' = [Wl; Wr] (512 x K) -> MFMA-fragment-ordered hi/lo planes.
// chunk ci = (kb*32 + ct)*64 + lane holds W'[ct*16 + (lane&15)][kb*32 + (lane>>4)*8 .. +8]
__global__ __launch_bounds__(256) void convert_w_frag(
    const float* __restrict__ Wl, const float* __restrict__ Wr,
    unsigned short* __restrict__ wfhi, unsigned short* __restrict__ wflo, int K) {
  int g = blockIdx.x * 256 + threadIdx.x;  // K*64 chunks
  int lane = g & 63;
  int ct = (g >> 6) & 31;
  int kb = g >> 11;
  int col = ct * 16 + (lane & 15);
  int k = kb * 32 + (lane >> 4) * 8;
  const float* src = (col < HC) ? &Wl[(size_t)col * K + k] : &Wr[(size_t)(col - HC) * K + k];
  float4 v0 = *(const float4*)src;
  float4 v1 = *(const float4*)(src + 4);
  uint4 hq, lq;
  split2(v0.x, v0.y, hq.x, lq.x);
  split2(v0.z, v0.w, hq.y, lq.y);
  split2(v1.x, v1.y, hq.z, lq.z);
  split2(v1.z, v1.w, hq.w, lq.w);
  *(uint4*)&wfhi[(size_t)g * 8] = hq;
  *(uint4*)&wflo[(size_t)g * 8] = lq;
}

// ---------- MFMA GEMM, LDS-free: [xl(bf16) | xr(fp32)] = X(hi/lo) @ W'(hi/lo)^T + bias ----
// 128x128 per block (XCD-swizzled grid), 4 waves, each 64x64 (4x4 MFMA 16x16x32).
// A fragments load directly global->VGPR row-major (16 full 64B lines per instr);
// B fragment-major (L2-resident). Register double-buffer, prefetch kb+1 under MFMA kb.
// No LDS, no barriers -> compiler emits fine-grained vmcnt, never vmcnt(0).
template <int K>
__global__ __launch_bounds__(256) void gemm_fused(
    const unsigned short* __restrict__ xhi, const unsigned short* __restrict__ xlo,
    const unsigned short* __restrict__ wfhi, const unsigned short* __restrict__ wflo,
    const float* __restrict__ bl, const float* __restrict__ br,
    unsigned short* __restrict__ Y1, float* __restrict__ Y2, int N, int nrb) {
  constexpr int nkb = K >> 5;
  // decode XCD-swizzled flat id: f = (rb%8) + 8*(cb + 4*(rb/8))
  const int f = blockIdx.x;
  const int rb = (f & 7) + 8 * (f >> 5);
  const int cb = (f >> 3) & 3;
  if (rb >= nrb) return;

  const int tid = threadIdx.x;
  const int wave = tid >> 6;
  const int lane = tid & 63;
  const int quad = lane >> 4;
  const int l16 = lane & 15;
  const int wr = (wave >> 1) * 64;
  const int wc = (wave & 1) * 64;
  const int row0 = rb * 128;
  const int col0 = cb * 128;
  const int ctg0 = cb * 8 + (wave & 1) * 4;  // wave's first col-tile (global)

  // per-lane A base offsets (ushort elems), rows clamped to N-1
  size_t abase[4];
#pragma unroll
  for (int i = 0; i < 4; i++) {
    int row = row0 + wr + i * 16 + l16;
    if (row >= N) row = N - 1;
    abase[i] = (size_t)row * K + quad * 8;
  }

  f32x4 acc[4][4];
#pragma unroll
  for (int i = 0; i < 4; i++)
#pragma unroll
    for (int j = 0; j < 4; j++) acc[i][j] = (f32x4){0.f, 0.f, 0.f, 0.f};

  bf16x8 ah[2][4], al[2][4], bh[2][4], bw[2][4];
  // prologue: fragments for k-tile 0
#pragma unroll
  for (int i = 0; i < 4; i++) {
    ah[0][i] = *(const bf16x8*)&xhi[abase[i]];
    al[0][i] = *(const bf16x8*)&xlo[abase[i]];
  }
#pragma unroll
  for (int j = 0; j < 4; j++) {
    size_t ci = (size_t)(ctg0 + j) * 64 + lane;
    bh[0][j] = *(const bf16x8*)&wfhi[ci * 8];
    bw[0][j] = *(const bf16x8*)&wflo[ci * 8];
  }

#pragma unroll
  for (int kb = 0; kb < nkb; kb++) {
    const int cur = kb & 1, nxt = cur ^ 1;
    if (kb + 1 < nkb) {  // prefetch kb+1 fragments under this tile's MFMAs
      const int koff = (kb + 1) * 32;
#pragma unroll
      for (int i = 0; i < 4; i++) {
        ah[nxt][i] = *(const bf16x8*)&xhi[abase[i] + koff];
        al[nxt][i] = *(const bf16x8*)&xlo[abase[i] + koff];
      }
#pragma unroll
      for (int j = 0; j < 4; j++) {
        size_t ci = ((size_t)(kb + 1) * 32 + ctg0 + j) * 64 + lane;
        bh[nxt][j] = *(const bf16x8*)&wfhi[ci * 8];
        bw[nxt][j] = *(const bf16x8*)&wflo[ci * 8];
      }
    }
#pragma unroll
    for (int i = 0; i < 4; i++)
#pragma unroll
      for (int j = 0; j < 4; j++) {
        acc[i][j] = __builtin_amdgcn_mfma_f32_16x16x32_bf16(ah[cur][i], bh[cur][j], acc[i][j], 0, 0, 0);
        acc[i][j] = __builtin_amdgcn_mfma_f32_16x16x32_bf16(ah[cur][i], bw[cur][j], acc[i][j], 0, 0, 0);
        acc[i][j] = __builtin_amdgcn_mfma_f32_16x16x32_bf16(al[cur][i], bh[cur][j], acc[i][j], 0, 0, 0);
      }
  }

  // epilogue: D row = quad*4+reg, col = l16; xl -> bf16 (RTN), xr -> fp32
#pragma unroll
  for (int j = 0; j < 4; j++) {
    int colg = col0 + wc + j * 16 + l16;  // 0..511
    if (colg < HC) {
      float bv = bl[colg];
#pragma unroll
      for (int i = 0; i < 4; i++)
#pragma unroll
        for (int r = 0; r < 4; r++) {
          int row = row0 + wr + i * 16 + quad * 4 + r;
          if (row < N)
            Y1[(size_t)row * HC + colg] = (unsigned short)rtn_bf16(acc[i][j][r] + bv);
        }
    } else {
      int cc = colg - HC;
      float bv = br[cc];
#pragma unroll
      for (int i = 0; i < 4; i++)
#pragma unroll
        for (int r = 0; r < 4; r++) {
          int row = row0 + wr + i * 16 + quad * 4 + r;
          if (row < N) Y2[(size_t)row * HC + cc] = acc[i][j][r] + bv;
        }
    }
  }
}

// ---------- CSR build (csr_src holds BYTE offsets into bf16 xl: src*512) ----------
__global__ __launch_bounds__(256) void hist_dst(
    const int* __restrict__ edst, int* __restrict__ counts, int E) {
  int e = blockIdx.x * 256 + threadIdx.x;
  if (e < E) atomicAdd(&counts[edst[e]], 1);
}

__global__ __launch_bounds__(256) void scan_blocks(
    const int* __restrict__ counts, int* __restrict__ row_start,
    int* __restrict__ bsum, int N) {
  __shared__ int tmp[256];
  int t = threadIdx.x;
  int base = blockIdx.x * 1024 + t * 4;
  int v0 = (base     < N) ? counts[base]     + 1 : 0;
  int v1 = (base + 1 < N) ? counts[base + 1] + 1 : 0;
  int v2 = (base + 2 < N) ? counts[base + 2] + 1 : 0;
  int v3 = (base + 3 < N) ? counts[base + 3] + 1 : 0;
  int c1 = v0 + v1, c2 = c1 + v2, tot = c2 + v3;
  tmp[t] = tot;
  __syncthreads();
  for (int off = 1; off < 256; off <<= 1) {
    int add = (t >= off) ? tmp[t - off] : 0;
    __syncthreads();
    tmp[t] += add;
    __syncthreads();
  }
  int excl = tmp[t] - tot;
  if (base     < N) row_start[base + 1] = excl + v0;
  if (base + 1 < N) row_start[base + 2] = excl + c1;
  if (base + 2 < N) row_start[base + 3] = excl + c2;
  if (base + 3 < N) row_start[base + 4] = excl + tot;
  if (t == 255) bsum[blockIdx.x] = tmp[255];
  if (blockIdx.x == 0 && t == 0) row_start[0] = 0;
}

__global__ void scan_tops(int* __restrict__ bsum, int nb) {
  int lane = threadIdx.x;
  int v = (lane < nb) ? bsum[lane] : 0;
  for (int off = 1; off < 64; off <<= 1) {
    int u = __shfl_up(v, off);
    if (lane >= off) v += u;
  }
  if (lane < nb) bsum[lane] = v;
}

__global__ __launch_bounds__(256) void scan_add(
    int* __restrict__ row_start, const int* __restrict__ bsum, int N) {
  int off = bsum[blockIdx.x];
  int i = (blockIdx.x + 1) * 1024 + threadIdx.x * 4;
#pragma unroll
  for (int k = 0; k < 4; k++)
    if (i + k < N) row_start[i + k + 1] += off;
}

__global__ __launch_bounds__(256) void csr_init(
    const int* __restrict__ row_start, int* __restrict__ fill_pos,
    int* __restrict__ csr_src, int N) {
  int i = blockIdx.x * 256 + threadIdx.x;
  if (i < N) {
    int p = row_start[i];
    csr_src[p] = i << 9;  // self-loop first, byte offset
    fill_pos[i] = p + 1;
  }
}

__global__ __launch_bounds__(256) void csr_scatter(
    const int* __restrict__ esrc, const int* __restrict__ edst,
    int* __restrict__ fill_pos, int* __restrict__ csr_src, int E) {
  int e = blockIdx.x * 256 + threadIdx.x;
  if (e < E) {
    int p = atomicAdd(&fill_pos[edst[e]], 1);
    csr_src[p] = esrc[e] << 9;  // byte offset
  }
}

// ---------- fused GATv2 edge phase: packed-f32 math, byte-offset gather ----------
__device__ __forceinline__ void unpk(uint2 q, f32x2& v01, f32x2& v23) {
  v01.x = __uint_as_float(q.x << 16);
  v01.y = __uint_as_float(q.x & 0xFFFF0000u);
  v23.x = __uint_as_float(q.y << 16);
  v23.y = __uint_as_float(q.y & 0xFFFF0000u);
}

__device__ __forceinline__ float edot(f32x2 l01, f32x2 l23, f32x2 r01, f32x2 r23,
                                      f32x2 a01, f32x2 a23) {
  f32x2 t01 = l01 + r01, t23 = l23 + r23;          // v_pk_add_f32
  f32x2 u01 = t01 * NEG_ATT, u23 = t23 * NEG_ATT;  // v_pk_mul_f32
  t01.x = fmaxf(t01.x, u01.x); t01.y = fmaxf(t01.y, u01.y);  // leaky = max(t,0.2t)
  t23.x = fmaxf(t23.x, u23.x); t23.y = fmaxf(t23.y, u23.y);
  f32x2 dv = t01 * a01 + t23 * a23;                // pk_mul + pk_fma
  float d = dv.x + dv.y;
  d += __shfl_xor(d, 1);
  d += __shfl_xor(d, 2);
  d += __shfl_xor(d, 4);
  d += __shfl_xor(d, 8);
  return d;
}

__global__ __launch_bounds__(256) void gat_fused(
    const unsigned short* __restrict__ xl, const float* __restrict__ xr,
    const int* __restrict__ row_start, const int* __restrict__ csr_soff,
    const float* __restrict__ att, const float* __restrict__ bo,
    float* __restrict__ outf, unsigned short* __restrict__ ohi,
    unsigned short* __restrict__ olo, int N, int split_out) {
  int dst = (blockIdx.x * 256 + threadIdx.x) >> 6;
  int lane = threadIdx.x & 63;
  if (dst >= N) return;
  int h = lane >> 4;
  int off = h * CH + (lane & 15) * 4;
  const int loff = off * 2;  // byte offset of this lane's 4 bf16 channels
  const char* xlc = (const char*)xl;
  f32x2 a01 = *(const f32x2*)&att[off];
  f32x2 a23 = *(const f32x2*)&att[off + 2];
  f32x2 r01 = *(const f32x2*)&xr[(size_t)dst * HC + off];
  f32x2 r23 = *(const f32x2*)&xr[(size_t)dst * HC + off + 2];
  f32x2 o01 = {0.f, 0.f}, o23 = {0.f, 0.f};
  float m = -__builtin_inff();
  float s = 0.f;
  int p = row_start[dst];
  int end = row_start[dst + 1];
  for (; p + 4 <= end; p += 4) {
    int b0 = csr_soff[p + 0] + loff, b1 = csr_soff[p + 1] + loff;
    int b2 = csr_soff[p + 2] + loff, b3 = csr_soff[p + 3] + loff;
    uint2 q0 = *(const uint2*)(xlc + b0);
    uint2 q1 = *(const uint2*)(xlc + b1);
    uint2 q2 = *(const uint2*)(xlc + b2);
    uint2 q3 = *(const uint2*)(xlc + b3);
    f32x2 l0a, l0b, l1a, l1b, l2a, l2b, l3a, l3b;
    unpk(q0, l0a, l0b);
    unpk(q1, l1a, l1b);
    unpk(q2, l2a, l2b);
    unpk(q3, l3a, l3b);
    float d0 = edot(l0a, l0b, r01, r23, a01, a23);
    float d1 = edot(l1a, l1b, r01, r23, a01, a23);
    float d2 = edot(l2a, l2b, r01, r23, a01, a23);
    float d3 = edot(l3a, l3b, r01, r23, a01, a23);
    float newm = fmaxf(fmaxf(fmaxf(d0, d1), fmaxf(d2, d3)), m);
    float sc = __expf(m - newm);
    float e0 = __expf(d0 - newm), e1 = __expf(d1 - newm);
    float e2 = __expf(d2 - newm), e3 = __expf(d3 - newm);
    s = fmaf(s, sc, (e0 + e1) + (e2 + e3));
    f32x2 acc01 = l0a * e0 + l1a * e1;
    acc01 = l2a * e2 + acc01;
    acc01 = l3a * e3 + acc01;
    o01 = o01 * sc + acc01;
    f32x2 acc23 = l0b * e0 + l1b * e1;
    acc23 = l2b * e2 + acc23;
    acc23 = l3b * e3 + acc23;
    o23 = o23 * sc + acc23;
    m = newm;
  }
  for (; p < end; p++) {
    int b0 = csr_soff[p] + loff;
    uint2 q0 = *(const uint2*)(xlc + b0);
    f32x2 la, lb;
    unpk(q0, la, lb);
    float d = edot(la, lb, r01, r23, a01, a23);
    float newm = fmaxf(m, d);
    float sc = __expf(m - newm);
    float pe = __expf(d - newm);
    s = fmaf(s, sc, pe);
    o01 = o01 * sc + la * pe;
    o23 = o23 * sc + lb * pe;
    m = newm;
  }
  float inv = 1.f / s;
  f32x2 b01 = *(const f32x2*)&bo[off];
  f32x2 b23 = *(const f32x2*)&bo[off + 2];
  f32x2 res01 = o01 * inv + b01;
  f32x2 res23 = o23 * inv + b23;
  if (split_out) {
    f32x2 v01 = res01 * NEG_ACT, v23 = res23 * NEG_ACT;
    res01.x = fmaxf(res01.x, v01.x); res01.y = fmaxf(res01.y, v01.y);
    res23.x = fmaxf(res23.x, v23.x); res23.y = fmaxf(res23.y, v23.y);
    uint2 h2, l2;
    split2(res01.x, res01.y, h2.x, l2.x);
    split2(res23.x, res23.y, h2.y, l2.y);
    *(uint2*)&ohi[(size_t)dst * HC + off] = h2;
    *(uint2*)&olo[(size_t)dst * HC + off] = l2;
  } else {
    float4 r4 = {res01.x, res01.y, res23.x, res23.y};
    *(float4*)&outf[(size_t)dst * HC + off] = r4;
  }
}

// ---------- pooling ----------
__global__ __launch_bounds__(256) void pool_partial(
    const float* __restrict__ h, const int* __restrict__ batch,
    float* __restrict__ out, int* __restrict__ cnt, int N) {
  __shared__ float part[NGRAPH][HC];
  __shared__ int bsh[256];
  __shared__ int cpart[NGRAPH];
  int j = threadIdx.x;
#pragma unroll
  for (int g = 0; g < NGRAPH; g++) part[g][j] = 0.f;
  if (j < NGRAPH) cpart[j] = 0;
  int n0 = blockIdx.x * 256;
  int nend = min(n0 + 256, N);
  int nj = n0 + j;
  bsh[j] = (nj < N) ? batch[nj] : 0;
  __syncthreads();
  if (nj < nend) atomicAdd(&cpart[bsh[j]], 1);
  for (int n = n0; n < nend; n++) {
    int g = bsh[n - n0];
    part[g][j] += h[(size_t)n * HC + j];
  }
  __syncthreads();
#pragma unroll
  for (int g = 0; g < NGRAPH; g++) {
    float v = part[g][j];
    if (v != 0.f) atomicAdd(&out[g * HC + j], v);
  }
  if (j < NGRAPH && cpart[j] > 0) atomicAdd(&cnt[j], cpart[j]);
}

__global__ __launch_bounds__(256) void pool_final(
    float* __restrict__ out, const int* __restrict__ cnt) {
  int g = blockIdx.x;
  int j = threadIdx.x;
  float c = (float)max(cnt[g], 1);
  out[g * HC + j] /= c;
}

extern "C" void kernel_launch(void* const* d_in, const int* in_sizes, int n_in,
                              void* d_out, int out_size, void* d_ws, size_t ws_size,
                              hipStream_t stream) {
  const float* x = (const float*)d_in[0];
  const int* ei = (const int*)d_in[1];
  const int* batch = (const int*)d_in[2];
  const int N = in_sizes[2];
  const int E = in_sizes[1] / 2;
  const int Etot = E + N;

  const float* Wl[3] = {(const float*)d_in[3], (const float*)d_in[9], (const float*)d_in[15]};
  const float* bl[3] = {(const float*)d_in[4], (const float*)d_in[10], (const float*)d_in[16]};
  const float* Wr[3] = {(const float*)d_in[5], (const float*)d_in[11], (const float*)d_in[17]};
  const float* br[3] = {(const float*)d_in[6], (const float*)d_in[12], (const float*)d_in[18]};
  const float* att[3] = {(const float*)d_in[7], (const float*)d_in[13], (const float*)d_in[19]};
  const float* bo[3] = {(const float*)d_in[8], (const float*)d_in[14], (const float*)d_in[20]};

  // ws layout
  float* B0 = (float*)d_ws;                 // planes region (layers 1-2) / fp32 h3 (layer 3)
  float* B1 = B0 + (size_t)N * HC;          // xl (bf16, half the slot)
  float* B2 = B1 + (size_t)N * HC;          // xr (fp32)
  unsigned short* w1hi = (unsigned short*)(B2 + (size_t)N * HC);
  unsigned short* w1lo = w1hi + 512 * 128;
  unsigned short* w2hi = w1lo + 512 * 128;
  unsigned short* w2lo = w2hi + 512 * 256;
  unsigned short* w3hi = w2lo + 512 * 256;
  unsigned short* w3lo = w3hi + 512 * 256;
  int* counts = (int*)(w3lo + 512 * 256);
  int* row_start = counts + N;
  int* bsum = row_start + N + 1;
  int* fill_pos = bsum + 64;
  int* csr_src = fill_pos + N;
  int* cnt = csr_src + Etot;

  unsigned short* xlB = (unsigned short*)B1;
  unsigned short* xhiL1 = (unsigned short*)B0;
  unsigned short* xloL1 = xhiL1 + (size_t)N * 128;
  unsigned short* xhiL = (unsigned short*)B0;
  unsigned short* xloL = xhiL + (size_t)N * HC;

  const int* esrc = ei;
  const int* edst = ei + E;

  // ---- conversions ----
  convert_x<<<(N * 128 / 4 + 255) / 256, 256, 0, stream>>>(x, xhiL1, xloL1, N * 128 / 4);
  convert_w_frag<<<128 * 64 / 256, 256, 0, stream>>>(Wl[0], Wr[0], w1hi, w1lo, 128);
  convert_w_frag<<<256 * 64 / 256, 256, 0, stream>>>(Wl[1], Wr[1], w2hi, w2lo, 256);
  convert_w_frag<<<256 * 64 / 256, 256, 0, stream>>>(Wl[2], Wr[2], w3hi, w3lo, 256);

  // ---- CSR build ----
  const int nscan = (N + 1023) / 1024;
  (void)hipMemsetAsync(counts, 0, (size_t)N * sizeof(int), stream);
  hist_dst<<<(E + 255) / 256, 256, 0, stream>>>(edst, counts, E);
  scan_blocks<<<nscan, 256, 0, stream>>>(counts, row_start, bsum, N);
  scan_tops<<<1, 64, 0, stream>>>(bsum, nscan);
  scan_add<<<nscan - 1, 256, 0, stream>>>(row_start, bsum, N);
  csr_init<<<(N + 255) / 256, 256, 0, stream>>>(row_start, fill_pos, csr_src, N);
  csr_scatter<<<(E + 255) / 256, 256, 0, stream>>>(esrc, edst, fill_pos, csr_src, E);

  const int nrb = (N + 127) / 128;                 // 391 row-blocks
  const int gblocks = ((nrb + 7) / 8) * 32;        // XCD-swizzled flat grid
  const int fblocks = (N * 64 + 255) / 256;

  // layer 1 (K=128)
  gemm_fused<128><<<gblocks, 256, 0, stream>>>(xhiL1, xloL1, w1hi, w1lo, bl[0], br[0], xlB, B2, N, nrb);
  gat_fused<<<fblocks, 256, 0, stream>>>(xlB, B2, row_start, csr_src, att[0], bo[0],
                                         nullptr, xhiL, xloL, N, 1);
  // layer 2 (K=256)
  gemm_fused<256><<<gblocks, 256, 0, stream>>>(xhiL, xloL, w2hi, w2lo, bl[1], br[1], xlB, B2, N, nrb);
  gat_fused<<<fblocks, 256, 0, stream>>>(xlB, B2, row_start, csr_src, att[1], bo[1],
                                         nullptr, xhiL, xloL, N, 1);
  // layer 3 (K=256), fp32 out for pooling
  gemm_fused<256><<<gblocks, 256, 0, stream>>>(xhiL, xloL, w3hi, w3lo, bl[2], br[2], xlB, B2, N, nrb);
  gat_fused<<<fblocks, 256, 0, stream>>>(xlB, B2, row_start, csr_src, att[2], bo[2],
                                         B0, nullptr, nullptr, N, 0);

  (void)hipMemsetAsync(d_out, 0, NGRAPH * HC * sizeof(float), stream);
  (void)hipMemsetAsync(cnt, 0, NGRAPH * sizeof(int), stream);
  pool_partial<<<(N + 255) / 256, 256, 0, stream>>>(B0, batch, (float*)d_out, cnt, N);
  pool_final<<<NGRAPH, 256, 0, stream>>>((float*)d_out, cnt);
}